// Round 1
// baseline (380.156 us; speedup 1.0000x reference)
//
#include <hip/hip_runtime.h>

#define T_TOK 16384
#define IN_F  1024
#define OUT_F 4096
#define NH    32

// ---------------------------------------------------------------------------
// K1: w_t[h][o] = amp[o][h] * cosf(phase[o][h])   (transposed for GEMM2 staging)
// ---------------------------------------------------------------------------
__global__ __launch_bounds__(256) void wreal_kernel(
    const float* __restrict__ phase, const float* __restrict__ amp,
    float* __restrict__ w_t)
{
    int idx = blockIdx.x * 256 + threadIdx.x;   // 0 .. 131071
    int o = idx & (OUT_F - 1);
    int h = idx >> 12;                          // idx / 4096
    float p = phase[o * NH + h];
    float a = amp[o * NH + h];
    w_t[h * OUT_F + o] = a * cosf(p);
}

// ---------------------------------------------------------------------------
// K2: res_t[h][t] = sum_i x[t][i] * basis[h][i]
// Zero-LDS, zero-barrier design. Block = 256 thr, 32 tokens.
// Thread (ty,tx): owns 2 tokens (2*ty, 2*ty+1) and K-slice {i0+4*tx..+3}.
// x loads: 16 tx-lanes x 16B = 256B contiguous per token row (coalesced, read
// exactly once chip-wide -> HBM-bound floor ~11us). basis (128 KB) read from
// L1/L2 with 4-way broadcast across ty groups.
// Per-lane partials pacc[2][32] (all compile-time indexed), then 4-step
// shfl_xor reduce-scatter over the 16 tx lanes: lane ends holding full sums
// for h0 and h0+1 where h0 = bit-scatter(tx). ~30 shuffles/token, one time.
// ---------------------------------------------------------------------------
#define K2_TT 32

__global__ __launch_bounds__(256, 2) void resonance_kernel(
    const float* __restrict__ x,      // [16384][1024]
    const float* __restrict__ basis,  // [32][1024]
    float* __restrict__ res_t)        // [32][16384]
{
    const int tid = threadIdx.x;
    const int ty  = tid >> 4;                 // 0..15 : token pair
    const int tx  = tid & 15;                 // K-slice
    const size_t ta = (size_t)blockIdx.x * K2_TT + 2 * ty;

    const float* xa = x + ta * IN_F + 4 * tx;
    const float* xb = xa + IN_F;
    const float* bp = basis + 4 * tx;

    float v0[NH] = {};
    float v1[NH] = {};

    float4 pa = *(const float4*)(xa);
    float4 pb = *(const float4*)(xb);

    for (int i0 = 0; i0 < IN_F; i0 += 64) {
        float4 ca = pa, cb = pb;
        if (i0 + 64 < IN_F) {                 // prefetch next chunk's x
            pa = *(const float4*)(xa + i0 + 64);
            pb = *(const float4*)(xb + i0 + 64);
        }
        #pragma unroll
        for (int hg = 0; hg < 4; ++hg) {
            float4 bv[8];
            #pragma unroll
            for (int h = 0; h < 8; ++h)
                bv[h] = *(const float4*)(bp + (size_t)(8 * hg + h) * IN_F + i0);
            #pragma unroll
            for (int h = 0; h < 8; ++h) {
                const int hh = 8 * hg + h;
                v0[hh] += ca.x * bv[h].x;
                v0[hh] += ca.y * bv[h].y;
                v0[hh] += ca.z * bv[h].z;
                v0[hh] += ca.w * bv[h].w;
                v1[hh] += cb.x * bv[h].x;
                v1[hh] += cb.y * bv[h].y;
                v1[hh] += cb.z * bv[h].z;
                v1[hh] += cb.w * bv[h].w;
            }
        }
    }

    // reduce-scatter across the 16 tx lanes (bits 0..3 of lane id).
    // Step s (mask m=1<<s, half=16>>s): pair (h, h+half); lane keeps the half
    // matching its tx bit, receives the other half from its partner.
    #pragma unroll
    for (int s = 0; s < 4; ++s) {
        const int m = 1 << s;
        const int half = 16 >> s;
        const bool up = (tx & m) != 0;
        #pragma unroll
        for (int h = 0; h < half; ++h) {
            float a0 = v0[h], b0 = v0[h + half];
            float k0 = up ? b0 : a0;
            float g0 = up ? a0 : b0;
            v0[h] = k0 + __shfl_xor(g0, m, 64);
            float a1 = v1[h], b1 = v1[h + half];
            float k1 = up ? b1 : a1;
            float g1 = up ? a1 : b1;
            v1[h] = k1 + __shfl_xor(g1, m, 64);
        }
    }

    // lane tx holds h0 = (tx0<<4)|(tx1<<3)|(tx2<<2)|(tx3<<1) and h0|1
    const int h0 = ((tx & 1) << 4) | ((tx & 2) << 2) | (tx & 4) | ((tx & 8) >> 2);
    *(float2*)(res_t + (size_t)h0 * T_TOK + ta)       = make_float2(v0[0], v1[0]);
    *(float2*)(res_t + (size_t)(h0 + 1) * T_TOK + ta) = make_float2(v0[1], v1[1]);
}

// ---------------------------------------------------------------------------
// K3: out[t][o] = sum_h res_t[h][t] * w_t[h][o]
// Tile 128 tokens x 256 outputs, 256 thr, thread = 8 tokens x 16 outputs.
// Per h-step: 6 ds_read_b128 -> 128 v_fmac  (LDS wall ~31us < 41us store wall
// -> store-bound). Strides 132/260 (== 4 mod 32) keep reads <=2-way (free).
// Stores: 4 float4 per token row, 1KB contiguous per row segment group.
// ---------------------------------------------------------------------------
#define G2_TT 128
#define G2_OT 256
#define RS_S  132
#define WT_S  260

__global__ __launch_bounds__(256, 2) void holo_out_kernel(
    const float* __restrict__ res_t,  // [32][16384]
    const float* __restrict__ w_t,    // [32][4096]
    float* __restrict__ out)          // [16384][4096]
{
    __shared__ float rs[NH * RS_S];   // 16.5 KB
    __shared__ float wl[NH * WT_S];   // 32.5 KB

    const int tid = threadIdx.x;
    const int o0  = blockIdx.x * G2_OT;
    const int t0  = blockIdx.y * G2_TT;
    const int ty  = tid >> 4;   // 0..15 : token group (8 tokens)
    const int tx  = tid & 15;   // output cols 4*tx + 64*j, j=0..3

    // stage res_t tile: 32 rows x 128 floats = 1024 float4 -> 4/thread
    #pragma unroll
    for (int it = 0; it < 4; ++it) {
        int lin = it * 256 + tid;
        int r = lin >> 5, c = lin & 31;           // 32 float4 per row
        float4 v = *(const float4*)(res_t + (size_t)r * T_TOK + t0 + 4 * c);
        *(float4*)(rs + r * RS_S + 4 * c) = v;
    }
    // stage w_t tile: 32 rows x 256 floats = 2048 float4 -> 8/thread
    #pragma unroll
    for (int it = 0; it < 8; ++it) {
        int lin = it * 256 + tid;
        int r = lin >> 6, c = lin & 63;           // 64 float4 per row
        float4 v = *(const float4*)(w_t + (size_t)r * OUT_F + o0 + 4 * c);
        *(float4*)(wl + r * WT_S + 4 * c) = v;
    }
    __syncthreads();

    float acc[8][16] = {};
    #pragma unroll
    for (int h = 0; h < NH; ++h) {
        float4 r0 = *(const float4*)(rs + h * RS_S + 8 * ty);
        float4 r1 = *(const float4*)(rs + h * RS_S + 8 * ty + 4);
        float4 w0 = *(const float4*)(wl + h * WT_S + 4 * tx);
        float4 w1 = *(const float4*)(wl + h * WT_S + 64 + 4 * tx);
        float4 w2 = *(const float4*)(wl + h * WT_S + 128 + 4 * tx);
        float4 w3 = *(const float4*)(wl + h * WT_S + 192 + 4 * tx);
        float r8[8]   = {r0.x, r0.y, r0.z, r0.w, r1.x, r1.y, r1.z, r1.w};
        float w16[16] = {w0.x, w0.y, w0.z, w0.w, w1.x, w1.y, w1.z, w1.w,
                         w2.x, w2.y, w2.z, w2.w, w3.x, w3.y, w3.z, w3.w};
        #pragma unroll
        for (int k = 0; k < 8; ++k)
            #pragma unroll
            for (int j = 0; j < 16; ++j)
                acc[k][j] += r8[k] * w16[j];
    }

    #pragma unroll
    for (int k = 0; k < 8; ++k) {
        float* po = out + (size_t)(t0 + 8 * ty + k) * OUT_F + o0;
        *(float4*)(po + 4 * tx)       = make_float4(acc[k][0],  acc[k][1],  acc[k][2],  acc[k][3]);
        *(float4*)(po + 64 + 4 * tx)  = make_float4(acc[k][4],  acc[k][5],  acc[k][6],  acc[k][7]);
        *(float4*)(po + 128 + 4 * tx) = make_float4(acc[k][8],  acc[k][9],  acc[k][10], acc[k][11]);
        *(float4*)(po + 192 + 4 * tx) = make_float4(acc[k][12], acc[k][13], acc[k][14], acc[k][15]);
    }
}

// ---------------------------------------------------------------------------
extern "C" void kernel_launch(void* const* d_in, const int* in_sizes, int n_in,
                              void* d_out, int out_size, void* d_ws, size_t ws_size,
                              hipStream_t stream)
{
    const float* x     = (const float*)d_in[0];  // [16384,1024]
    const float* basis = (const float*)d_in[1];  // [32,1024]
    const float* phase = (const float*)d_in[2];  // [4096,32]
    const float* amp   = (const float*)d_in[3];  // [4096,32]
    float* out = (float*)d_out;                  // [16384,4096] fp32

    float* res_t = (float*)d_ws;                       // 32*16384 floats = 2 MB
    float* w_t   = res_t + (size_t)NH * T_TOK;         // 32*4096 floats = 512 KB

    wreal_kernel<<<dim3((OUT_F * NH) / 256), dim3(256), 0, stream>>>(phase, amp, w_t);
    resonance_kernel<<<dim3(T_TOK / K2_TT), dim3(256), 0, stream>>>(x, basis, res_t);
    holo_out_kernel<<<dim3(OUT_F / G2_OT, T_TOK / G2_TT), dim3(256), 0, stream>>>(res_t, w_t, out);
}

// Round 2
// 362.251 us; speedup vs baseline: 1.0494x; 1.0494x over previous
//
#include <hip/hip_runtime.h>

#define T_TOK 16384
#define IN_F  1024
#define OUT_F 4096
#define NH    32

// ---------------------------------------------------------------------------
// K1: w_t[h][o] = amp[o][h] * cosf(phase[o][h])   (transposed for GEMM2 staging)
// ---------------------------------------------------------------------------
__global__ __launch_bounds__(256) void wreal_kernel(
    const float* __restrict__ phase, const float* __restrict__ amp,
    float* __restrict__ w_t)
{
    int idx = blockIdx.x * 256 + threadIdx.x;   // 0 .. 131071
    int o = idx & (OUT_F - 1);
    int h = idx >> 12;                          // idx / 4096
    float p = phase[o * NH + h];
    float a = amp[o * NH + h];
    w_t[h * OUT_F + o] = a * cosf(p);
}

// ---------------------------------------------------------------------------
// K2: res_t[h][t] = sum_i x[t][i] * basis[h][i]
// Zero-LDS, zero-barrier design (round-1 version, kept). Block = 256 thr,
// 32 tokens. Thread (ty,tx): 2 tokens, K-slice 4*tx. x read exactly once
// (coalesced 256B/row-inst); basis from L1/L2 broadcast. Per-lane partials
// v0/v1[32] all compile-time indexed; 4-step shfl_xor reduce-scatter.
// ---------------------------------------------------------------------------
#define K2_TT 32

__global__ __launch_bounds__(256, 2) void resonance_kernel(
    const float* __restrict__ x,      // [16384][1024]
    const float* __restrict__ basis,  // [32][1024]
    float* __restrict__ res_t)        // [32][16384]
{
    const int tid = threadIdx.x;
    const int ty  = tid >> 4;                 // 0..15 : token pair
    const int tx  = tid & 15;                 // K-slice
    const size_t ta = (size_t)blockIdx.x * K2_TT + 2 * ty;

    const float* xa = x + ta * IN_F + 4 * tx;
    const float* xb = xa + IN_F;
    const float* bp = basis + 4 * tx;

    float v0[NH] = {};
    float v1[NH] = {};

    float4 pa = *(const float4*)(xa);
    float4 pb = *(const float4*)(xb);

    for (int i0 = 0; i0 < IN_F; i0 += 64) {
        float4 ca = pa, cb = pb;
        if (i0 + 64 < IN_F) {                 // prefetch next chunk's x
            pa = *(const float4*)(xa + i0 + 64);
            pb = *(const float4*)(xb + i0 + 64);
        }
        #pragma unroll
        for (int hg = 0; hg < 4; ++hg) {
            float4 bv[8];
            #pragma unroll
            for (int h = 0; h < 8; ++h)
                bv[h] = *(const float4*)(bp + (size_t)(8 * hg + h) * IN_F + i0);
            #pragma unroll
            for (int h = 0; h < 8; ++h) {
                const int hh = 8 * hg + h;
                v0[hh] += ca.x * bv[h].x;
                v0[hh] += ca.y * bv[h].y;
                v0[hh] += ca.z * bv[h].z;
                v0[hh] += ca.w * bv[h].w;
                v1[hh] += cb.x * bv[h].x;
                v1[hh] += cb.y * bv[h].y;
                v1[hh] += cb.z * bv[h].z;
                v1[hh] += cb.w * bv[h].w;
            }
        }
    }

    // reduce-scatter across the 16 tx lanes (bits 0..3 of lane id).
    #pragma unroll
    for (int s = 0; s < 4; ++s) {
        const int m = 1 << s;
        const int half = 16 >> s;
        const bool up = (tx & m) != 0;
        #pragma unroll
        for (int h = 0; h < half; ++h) {
            float a0 = v0[h], b0 = v0[h + half];
            float k0 = up ? b0 : a0;
            float g0 = up ? a0 : b0;
            v0[h] = k0 + __shfl_xor(g0, m, 64);
            float a1 = v1[h], b1 = v1[h + half];
            float k1 = up ? b1 : a1;
            float g1 = up ? a1 : b1;
            v1[h] = k1 + __shfl_xor(g1, m, 64);
        }
    }

    // lane tx holds h0 and h0+1
    const int h0 = ((tx & 1) << 4) | ((tx & 2) << 2) | (tx & 4) | ((tx & 8) >> 2);
    *(float2*)(res_t + (size_t)h0 * T_TOK + ta)       = make_float2(v0[0], v1[0]);
    *(float2*)(res_t + (size_t)(h0 + 1) * T_TOK + ta) = make_float2(v0[1], v1[1]);
}

// ---------------------------------------------------------------------------
// K3: out[t][o] = sum_h res_t[h][t] * w_t[h][o]
// ROUND-0 VERBATIM (known-good 353us configuration).
// Block: 256 thr, tile 64 tokens x 128 outputs, K=32 fully in LDS (one stage).
// Thread = 4 tokens x 8 outputs. Per h-step: 3 ds_read_b128 -> 32 v_fmac.
// ---------------------------------------------------------------------------
#define G2_TT 64
#define G2_OT 128
#define RS_S  68
#define WT_S  132

__global__ __launch_bounds__(256) void holo_out_kernel(
    const float* __restrict__ res_t,  // [32][16384]
    const float* __restrict__ w_t,    // [32][4096]
    float* __restrict__ out)          // [16384][4096]
{
    __shared__ float rs[NH * RS_S];   // 8.7 KB
    __shared__ float wl[NH * WT_S];   // 16.9 KB

    const int tid = threadIdx.x;
    const int o0  = blockIdx.x * G2_OT;
    const int t0  = blockIdx.y * G2_TT;
    const int ty  = tid >> 4;   // 0..15 : token group (4 tokens)
    const int tx  = tid & 15;   // output cols 4*tx and 64+4*tx

    // stage res_t tile: 32 rows x 64 floats = 512 float4 -> 2/thread
    #pragma unroll
    for (int it = 0; it < 2; ++it) {
        int lin = it * 256 + tid;                 // 0..511
        int r = lin >> 4, c = lin & 15;           // 16 float4 per row
        float4 v = *(const float4*)(res_t + (size_t)r * T_TOK + t0 + 4 * c);
        *(float4*)(rs + r * RS_S + 4 * c) = v;
    }
    // stage w_t tile: 32 rows x 128 floats = 1024 float4 -> 4/thread
    #pragma unroll
    for (int it = 0; it < 4; ++it) {
        int lin = it * 256 + tid;
        int r = lin >> 5, c = lin & 31;
        float4 v = *(const float4*)(w_t + (size_t)r * OUT_F + o0 + 4 * c);
        *(float4*)(wl + r * WT_S + 4 * c) = v;
    }
    __syncthreads();

    float acc[4][8] = {};
    #pragma unroll
    for (int h = 0; h < NH; ++h) {
        float4 rt = *(const float4*)(rs + h * RS_S + 4 * ty);
        float4 wa = *(const float4*)(wl + h * WT_S + 4 * tx);
        float4 wb = *(const float4*)(wl + h * WT_S + 64 + 4 * tx);
        float r4[4] = {rt.x, rt.y, rt.z, rt.w};
        float w8[8] = {wa.x, wa.y, wa.z, wa.w, wb.x, wb.y, wb.z, wb.w};
        #pragma unroll
        for (int k = 0; k < 4; ++k)
            #pragma unroll
            for (int j = 0; j < 8; ++j)
                acc[k][j] += r4[k] * w8[j];
    }

    #pragma unroll
    for (int k = 0; k < 4; ++k) {
        float* po = out + (size_t)(t0 + 4 * ty + k) * OUT_F + o0;
        *(float4*)(po + 4 * tx)      = make_float4(acc[k][0], acc[k][1], acc[k][2], acc[k][3]);
        *(float4*)(po + 64 + 4 * tx) = make_float4(acc[k][4], acc[k][5], acc[k][6], acc[k][7]);
    }
}

// ---------------------------------------------------------------------------
extern "C" void kernel_launch(void* const* d_in, const int* in_sizes, int n_in,
                              void* d_out, int out_size, void* d_ws, size_t ws_size,
                              hipStream_t stream)
{
    const float* x     = (const float*)d_in[0];  // [16384,1024]
    const float* basis = (const float*)d_in[1];  // [32,1024]
    const float* phase = (const float*)d_in[2];  // [4096,32]
    const float* amp   = (const float*)d_in[3];  // [4096,32]
    float* out = (float*)d_out;                  // [16384,4096] fp32

    float* res_t = (float*)d_ws;                       // 32*16384 floats = 2 MB
    float* w_t   = res_t + (size_t)NH * T_TOK;         // 32*4096 floats = 512 KB

    wreal_kernel<<<dim3((OUT_F * NH) / 256), dim3(256), 0, stream>>>(phase, amp, w_t);
    resonance_kernel<<<dim3(T_TOK / K2_TT), dim3(256), 0, stream>>>(x, basis, res_t);
    holo_out_kernel<<<dim3(OUT_F / G2_OT, T_TOK / G2_TT), dim3(256), 0, stream>>>(res_t, w_t, out);
}

// Round 3
// 359.215 us; speedup vs baseline: 1.0583x; 1.0085x over previous
//
#include <hip/hip_runtime.h>

#define T_TOK 16384
#define IN_F  1024
#define OUT_F 4096
#define NH    32

// ---------------------------------------------------------------------------
// K1: w_t[h][o] = amp[o][h] * cosf(phase[o][h])   (transposed for GEMM2 staging)
// ---------------------------------------------------------------------------
__global__ __launch_bounds__(256) void wreal_kernel(
    const float* __restrict__ phase, const float* __restrict__ amp,
    float* __restrict__ w_t)
{
    int idx = blockIdx.x * 256 + threadIdx.x;   // 0 .. 131071
    int o = idx & (OUT_F - 1);
    int h = idx >> 12;                          // idx / 4096
    float p = phase[o * NH + h];
    float a = amp[o * NH + h];
    w_t[h * OUT_F + o] = a * cosf(p);
}

// ---------------------------------------------------------------------------
// K2: res_t[h][t] = sum_i x[t][i] * basis[h][i]
// ROUND-0 VERBATIM (known-best). Block: 256 thr, 64 tokens, K-chunks of 128.
// Thread = 4 tokens x 2 harmonics. LDS strides 132 -> <=2-way (free) reads.
// ---------------------------------------------------------------------------
#define G1_TT 64
#define G1_KC 128
#define G1_S  132

__global__ __launch_bounds__(256) void resonance_kernel(
    const float* __restrict__ x,      // [16384][1024]
    const float* __restrict__ basis,  // [32][1024]
    float* __restrict__ res_t)        // [32][16384]
{
    __shared__ float xs[G1_TT * G1_S];   // 33.8 KB
    __shared__ float bs[NH * G1_S];      // 16.9 KB

    const int tid = threadIdx.x;
    const int t0  = blockIdx.x * G1_TT;
    const int ty  = tid >> 4;   // 0..15 : token group (4 tokens)
    const int tx  = tid & 15;   // h = tx, tx+16

    float acc[4][2] = {};

    for (int i0 = 0; i0 < IN_F; i0 += G1_KC) {
        // stage x tile: 64 rows x 128 floats = 2048 float4 / 256 thr = 8 each
        #pragma unroll
        for (int it = 0; it < 8; ++it) {
            int lin = it * 256 + tid;
            int r = lin >> 5, c = lin & 31;           // 32 float4 per row
            float4 v = *(const float4*)(x + (size_t)(t0 + r) * IN_F + i0 + 4 * c);
            *(float4*)(xs + r * G1_S + 4 * c) = v;
        }
        // stage basis tile: 32 x 128 = 1024 float4 / 256 thr = 4 each
        #pragma unroll
        for (int it = 0; it < 4; ++it) {
            int lin = it * 256 + tid;
            int r = lin >> 5, c = lin & 31;
            float4 v = *(const float4*)(basis + (size_t)r * IN_F + i0 + 4 * c);
            *(float4*)(bs + r * G1_S + 4 * c) = v;
        }
        __syncthreads();

        #pragma unroll 4
        for (int i = 0; i < G1_KC; i += 4) {
            float4 xa[4], bb[2];
            #pragma unroll
            for (int k = 0; k < 4; ++k)
                xa[k] = *(const float4*)(xs + (4 * ty + k) * G1_S + i);
            #pragma unroll
            for (int j = 0; j < 2; ++j)
                bb[j] = *(const float4*)(bs + (tx + 16 * j) * G1_S + i);
            #pragma unroll
            for (int k = 0; k < 4; ++k) {
                #pragma unroll
                for (int j = 0; j < 2; ++j) {
                    acc[k][j] += xa[k].x * bb[j].x;
                    acc[k][j] += xa[k].y * bb[j].y;
                    acc[k][j] += xa[k].z * bb[j].z;
                    acc[k][j] += xa[k].w * bb[j].w;
                }
            }
        }
        __syncthreads();
    }

    #pragma unroll
    for (int k = 0; k < 4; ++k)
        #pragma unroll
        for (int j = 0; j < 2; ++j)
            res_t[(size_t)(tx + 16 * j) * T_TOK + t0 + 4 * ty + k] = acc[k][j];
}

// ---------------------------------------------------------------------------
// K3: out[t][o] = sum_h res_t[h][t] * w_t[h][o]
// Tile 128 tokens x 128 outputs, 256 thr, thread = 8 tokens x 8 outputs.
// Per h-step: 4 ds_read_b128 -> 64 v_fmac. LDS wall ~41us == store wall ~42us
// (K3-old was 3 reads / 32 fmac -> 61us LDS-bound; K3-r1's acc[8][16] blew
// register budget). acc[8][8]=64 VGPR, LDS 33KB -> 3-4 blocks/CU.
// r-reads: 16-lane broadcast; w-reads: 2-way (free). Stores 256B/16-lane.
// ---------------------------------------------------------------------------
#define G2_TT 128
#define G2_OT 128
#define RS_S  132
#define WT_S  132

__global__ __launch_bounds__(256) void holo_out_kernel(
    const float* __restrict__ res_t,  // [32][16384]
    const float* __restrict__ w_t,    // [32][4096]
    float* __restrict__ out)          // [16384][4096]
{
    __shared__ float rs[NH * RS_S];   // 16.5 KB
    __shared__ float wl[NH * WT_S];   // 16.5 KB

    const int tid = threadIdx.x;
    const int o0  = blockIdx.x * G2_OT;
    const int t0  = blockIdx.y * G2_TT;
    const int ty  = tid >> 4;   // 0..15 : token group (8 tokens)
    const int tx  = tid & 15;   // output cols 4*tx and 64+4*tx

    // stage res_t tile: 32 rows x 128 floats = 1024 float4 -> 4/thread
    #pragma unroll
    for (int it = 0; it < 4; ++it) {
        int lin = it * 256 + tid;
        int r = lin >> 5, c = lin & 31;           // 32 float4 per row
        float4 v = *(const float4*)(res_t + (size_t)r * T_TOK + t0 + 4 * c);
        *(float4*)(rs + r * RS_S + 4 * c) = v;
    }
    // stage w_t tile: 32 rows x 128 floats = 1024 float4 -> 4/thread
    #pragma unroll
    for (int it = 0; it < 4; ++it) {
        int lin = it * 256 + tid;
        int r = lin >> 5, c = lin & 31;
        float4 v = *(const float4*)(w_t + (size_t)r * OUT_F + o0 + 4 * c);
        *(float4*)(wl + r * WT_S + 4 * c) = v;
    }
    __syncthreads();

    float acc[8][8] = {};
    #pragma unroll
    for (int h = 0; h < NH; ++h) {
        float4 r0 = *(const float4*)(rs + h * RS_S + 8 * ty);
        float4 r1 = *(const float4*)(rs + h * RS_S + 8 * ty + 4);
        float4 wa = *(const float4*)(wl + h * WT_S + 4 * tx);
        float4 wb = *(const float4*)(wl + h * WT_S + 64 + 4 * tx);
        float r8[8] = {r0.x, r0.y, r0.z, r0.w, r1.x, r1.y, r1.z, r1.w};
        float w8[8] = {wa.x, wa.y, wa.z, wa.w, wb.x, wb.y, wb.z, wb.w};
        #pragma unroll
        for (int k = 0; k < 8; ++k)
            #pragma unroll
            for (int j = 0; j < 8; ++j)
                acc[k][j] += r8[k] * w8[j];
    }

    #pragma unroll
    for (int k = 0; k < 8; ++k) {
        float* po = out + (size_t)(t0 + 8 * ty + k) * OUT_F + o0;
        *(float4*)(po + 4 * tx)      = make_float4(acc[k][0], acc[k][1], acc[k][2], acc[k][3]);
        *(float4*)(po + 64 + 4 * tx) = make_float4(acc[k][4], acc[k][5], acc[k][6], acc[k][7]);
    }
}

// ---------------------------------------------------------------------------
extern "C" void kernel_launch(void* const* d_in, const int* in_sizes, int n_in,
                              void* d_out, int out_size, void* d_ws, size_t ws_size,
                              hipStream_t stream)
{
    const float* x     = (const float*)d_in[0];  // [16384,1024]
    const float* basis = (const float*)d_in[1];  // [32,1024]
    const float* phase = (const float*)d_in[2];  // [4096,32]
    const float* amp   = (const float*)d_in[3];  // [4096,32]
    float* out = (float*)d_out;                  // [16384,4096] fp32

    float* res_t = (float*)d_ws;                       // 32*16384 floats = 2 MB
    float* w_t   = res_t + (size_t)NH * T_TOK;         // 32*4096 floats = 512 KB

    wreal_kernel<<<dim3((OUT_F * NH) / 256), dim3(256), 0, stream>>>(phase, amp, w_t);
    resonance_kernel<<<dim3(T_TOK / G1_TT), dim3(256), 0, stream>>>(x, basis, res_t);
    holo_out_kernel<<<dim3(OUT_F / G2_OT, T_TOK / G2_TT), dim3(256), 0, stream>>>(res_t, w_t, out);
}